// Round 11
// baseline (293.353 us; speedup 1.0000x reference)
//
#include <hip/hip_runtime.h>
#include <hip/hip_bf16.h>

#define BS_   4096
#define NQ_   21
#define NK_   7
#define E_    512
#define MQ_   (BS_*NQ_)   // 86016 q rows
#define MK_   (BS_*NK_)   // 28672 k rows
#define MTQ_  (MQ_/64)    // 1344 q 64-row tiles
#define MTK_  (MK_/64)    // 448 k 64-row tiles
#define MTT_  (MTQ_+MTK_) // 1792 total
#define SCALE_ 2.88539008177792681f   // 2*log2(e): exp2(SCALE*x) = e^{2x}

typedef __attribute__((ext_vector_type(8))) short bf16x8;
typedef __attribute__((ext_vector_type(4))) float f32x4;
typedef __attribute__((ext_vector_type(8))) unsigned short u16x8;

__device__ __forceinline__ unsigned int cvt_pk_bf16(float lo, float hi){
  unsigned int r;
  asm("v_cvt_pk_bf16_f32 %0, %1, %2" : "=v"(r) : "v"(lo), "v"(hi));
  return r;
}
__device__ __forceinline__ float bf2f(unsigned short h){
  return __builtin_bit_cast(float, (unsigned int)h << 16);
}

// ---------------- weight cast f32 -> bf16 ----------------
__global__ __launch_bounds__(256) void cast_weights(
    const float* __restrict__ wq, const float* __restrict__ wk,
    unsigned int* __restrict__ oq, unsigned int* __restrict__ ok)
{
  int i = blockIdx.x * 256 + threadIdx.x;           // 65536 float4s each
  float4 a = ((const float4*)wq)[i];
  float4 b = ((const float4*)wk)[i];
  uint2 ua = { cvt_pk_bf16(a.x, a.y), cvt_pk_bf16(a.z, a.w) };
  uint2 ub = { cvt_pk_bf16(b.x, b.y), cvt_pk_bf16(b.z, b.w) };
  ((uint2*)oq)[i] = ua;
  ((uint2*)ok)[i] = ub;
}

// ---------------- merged projection GEMMs, B-direct-from-L2 -----------------
// C[m,h] = (sum_e A[m,e]*W[h,e] + bias[h]) * SCALE, bf16 out.
// Block = 64 rows x 256 cols; 4 waves stacked on N, each wave 64x64.
// B (bf16 weights, 512 KB, L2-resident) is read DIRECTLY from global as MFMA
// fragments, prefetched one K-step ahead in registers -- no B in LDS at all.
// A (f32) is reg-staged -> cvt_pk -> one shared 4 KB bf16 LDS tile per step
// (double-buffered, depth-2 global prefetch via avA/avB parity).
// LDS traffic per block-step: 4 KB write + 16 KB read (was 48 KB in r10).
// Raw s_barrier + lgkmcnt(0) only; vmem waits left to the compiler's exact
// counting. Swizzle/maps reuse r9/r10's measured-0-conflict patterns.
__global__ __launch_bounds__(256)
void gemm_proj(const float* __restrict__ Aq, const float* __restrict__ Ak,
               const unsigned short* __restrict__ Bq, const unsigned short* __restrict__ Bk,
               const float* __restrict__ bq, const float* __restrict__ bk,
               unsigned short* __restrict__ Cq, unsigned short* __restrict__ Ck)
{
  __shared__ char Asm[2][64 * 64];   // 4 KB each: bf16 A-tile [64 rows][64 B]

  const int tid  = threadIdx.x;
  const int lane = tid & 63;
  const int w    = tid >> 6;

  // XCD-grouped bijection (3584 blocks % 8 == 0): ntb fastest per XCD.
  const int bid = (int)blockIdx.x;
  const int j   = bid >> 3;
  int       mt  = (j >> 1) * 8 + (bid & 7);   // 0..1791
  const int ntb = j & 1;                      // 0..1 (256-col halves)

  const float* A; const unsigned short* Bw; const float* bias; unsigned short* C;
  if (mt < MTQ_){ A = Aq; Bw = Bq; bias = bq; C = Cq; }
  else          { A = Ak; Bw = Bk; bias = bk; C = Ck; mt -= MTQ_; }

  const long m0  = (long)mt << 6;            // 64-row tile base
  const int  n0w = ntb * 256 + w * 64;       // this wave's 64-col base
  const char* Abyte = (const char*)(A + m0 * E_);

  // ---- A staging map: 2 x (16B f32 in -> 8B bf16 out) per thread per K-step
  //      (r9's measured-0-conflict write pattern)
  long asrc[2]; int adst[2];
#pragma unroll
  for (int i = 0; i < 2; ++i){
    const int c   = tid + i * 256;           // chunk 0..511 (16 B f32 each)
    const int row = c >> 3;                  // 8 chunks per 128-B f32 row
    const int sl  = c & 7;
    asrc[i] = (long)row * (E_ * 4) + sl * 16;
    adst[i] = row * 64 + (((sl & 6) * 8) ^ (((row >> 1) & 3) << 4)) + (sl & 1) * 8;
  }
  // ---- A fragment-read offsets (r9's measured-0-conflict read pattern)
  int aoff[4];
#pragma unroll
  for (int m = 0; m < 4; ++m){
    const int r = m * 16 + (lane & 15);
    aoff[m] = r * 64 + ((16 * (lane >> 4)) ^ (((r >> 1) & 3) << 4));
  }
  // ---- B direct per-lane base: col = n0w + (lane&15) (+n*16), k-slot (lane>>4)*8
  const unsigned short* Bp = Bw + (long)(n0w + (lane & 15)) * E_ + (lane >> 4) * 8;

  f32x4 acc[4][4];
  const f32x4 z4 = {0.f, 0.f, 0.f, 0.f};
#pragma unroll
  for (int m = 0; m < 4; ++m)
#pragma unroll
    for (int n = 0; n < 4; ++n) acc[m][n] = z4;

  bf16x8 bfrC[4], bfrN[4];
  float4 avA[2], avB[2];

#define LOAD_A(av, T) do { \
  _Pragma("unroll") for (int i_ = 0; i_ < 2; ++i_) \
    av[i_] = *(const float4*)(Abyte + asrc[i_] + (long)(T) * 128); \
} while(0)

#define LOAD_B(dst, T) do { \
  _Pragma("unroll") for (int n_ = 0; n_ < 4; ++n_) \
    dst[n_] = *(const bf16x8*)(Bp + (long)n_ * 16 * E_ + (T) * 32); \
} while(0)

#define WRITE_A(BUF, av) do { \
  _Pragma("unroll") for (int i_ = 0; i_ < 2; ++i_){ \
    uint2 u_ = { cvt_pk_bf16(av[i_].x, av[i_].y), cvt_pk_bf16(av[i_].z, av[i_].w) }; \
    *(uint2*)(Asm[BUF] + adst[i_]) = u_; \
  } \
} while(0)

#define COMPUTE(BUF) do { \
  bf16x8 af_[4]; \
  _Pragma("unroll") for (int m_ = 0; m_ < 4; ++m_) \
    af_[m_] = *(const bf16x8*)(Asm[BUF] + aoff[m_]); \
  _Pragma("unroll") for (int m_ = 0; m_ < 4; ++m_) \
    _Pragma("unroll") for (int n_ = 0; n_ < 4; ++n_) \
      acc[m_][n_] = __builtin_amdgcn_mfma_f32_16x16x32_bf16(af_[m_], bfrC[n_], acc[m_][n_], 0, 0, 0); \
} while(0)

#define BAR() do { \
  asm volatile("s_waitcnt lgkmcnt(0)" ::: "memory"); \
  __builtin_amdgcn_s_barrier(); \
  __builtin_amdgcn_sched_barrier(0); \
} while(0)

#define STEP(T, AVISS, AVWR) do { \
  LOAD_A(AVISS, (T) + 2); \
  LOAD_B(bfrN, (T) + 1); \
  COMPUTE((T) & 1); \
  WRITE_A(((T) + 1) & 1, AVWR); \
  BAR(); \
  _Pragma("unroll") for (int n_ = 0; n_ < 4; ++n_) bfrC[n_] = bfrN[n_]; \
} while(0)

  // ---- prologue: A(0),A(1) in regs; B(0) in regs; write A(0) to buf0
  LOAD_A(avA, 0);
  LOAD_A(avB, 1);
  LOAD_B(bfrC, 0);
  WRITE_A(0, avA);
  BAR();

  // ---- main loop: 16 K-steps of 32 (t = 0..13 paired, 14/15 peeled)
#pragma unroll
  for (int tp = 0; tp < 7; ++tp){
    const int t = tp * 2;
    STEP(t,     avA, avB);   // issue A(t+2) into avA, write A(t+1) from avB
    STEP(t + 1, avB, avA);   // issue A(t+3) into avB, write A(t+2) from avA
  }
  // t = 14: no A(16); write A(15) from avB
  {
    LOAD_B(bfrN, 15);
    COMPUTE(0);
    WRITE_A(1, avB);
    BAR();
#pragma unroll
    for (int n_ = 0; n_ < 4; ++n_) bfrC[n_] = bfrN[n_];
  }
  // t = 15
  COMPUTE(1);

#undef LOAD_A
#undef LOAD_B
#undef WRITE_A
#undef COMPUTE
#undef BAR
#undef STEP

  // ---- epilogue: v = (acc + bias)*SCALE, bf16 store
  // C/D layout: col = lane&15 (+n*16), row = (lane>>4)*4 + j
  const int ccol0 = n0w + (lane & 15);
  float bvs[4];
#pragma unroll
  for (int n = 0; n < 4; ++n) bvs[n] = bias[ccol0 + n * 16] * SCALE_;
#pragma unroll
  for (int m = 0; m < 4; ++m){
    const long rbase = m0 + m * 16 + (lane >> 4) * 4;
#pragma unroll
    for (int n = 0; n < 4; ++n){
      const long col = ccol0 + n * 16;
      float v0 = fmaf(acc[m][n][0], SCALE_, bvs[n]);
      float v1 = fmaf(acc[m][n][1], SCALE_, bvs[n]);
      float v2 = fmaf(acc[m][n][2], SCALE_, bvs[n]);
      float v3 = fmaf(acc[m][n][3], SCALE_, bvs[n]);
      unsigned int u01 = cvt_pk_bf16(v0, v1);
      unsigned int u23 = cvt_pk_bf16(v2, v3);
      C[(rbase + 0) * E_ + col] = (unsigned short)(u01 & 0xffffu);
      C[(rbase + 1) * E_ + col] = (unsigned short)(u01 >> 16);
      C[(rbase + 2) * E_ + col] = (unsigned short)(u23 & 0xffffu);
      C[(rbase + 3) * E_ + col] = (unsigned short)(u23 >> 16);
    }
  }
}

// ---------------- fused score + softmax + weighted sum ----------------
// One WAVE per batch. q'', k'' are bf16 pre-scaled by 2*log2(e).
// score(q,k) = sum_h wv_h * tanh(q+k) = Wsum - 2*sum_h wv_h / (1 + e^{2(q+k)})
__global__ __launch_bounds__(256, 2)
void attn_fused(const unsigned short* __restrict__ qp,
                const unsigned short* __restrict__ kp,
                const float* __restrict__ keys,
                const float* __restrict__ wv, const float* __restrict__ wvb,
                const int* __restrict__ mask,
                float* __restrict__ out0, float* __restrict__ out1)
{
  const int lane = threadIdx.x & 63;
  const int b    = blockIdx.x * 4 + (threadIdx.x >> 6);

  // per-lane wv slice (h = lane*8 .. +7)
  float wvr[8];
  *(float4*)&wvr[0] = ((const float4*)wv)[lane * 2];
  *(float4*)&wvr[4] = ((const float4*)wv)[lane * 2 + 1];

  // k'' rows -> f32 regs [7][8]
  float kf[NK_][8];
#pragma unroll
  for (int k = 0; k < NK_; ++k){
    u16x8 u = *(const u16x8*)(kp + ((long)b * NK_ + k) * E_ + lane * 8);
#pragma unroll
    for (int j = 0; j < 8; ++j) kf[k][j] = bf2f((unsigned short)u[j]);
  }
  // raw keys -> f32 regs [7][8]
  float kr[NK_][8];
#pragma unroll
  for (int k = 0; k < NK_; ++k){
    const float4* p = (const float4*)(keys + ((long)b * NK_ + k) * E_ + lane * 8);
    *(float4*)&kr[k][0] = p[0];
    *(float4*)&kr[k][4] = p[1];
  }

  // Wsum = sum_h wv_h (butterfly over lanes)
  float wsum = ((wvr[0] + wvr[1]) + (wvr[2] + wvr[3])) + ((wvr[4] + wvr[5]) + (wvr[6] + wvr[7]));
#pragma unroll
  for (int off = 32; off; off >>= 1) wsum += __shfl_xor(wsum, off, 64);

  const float vb = wvb[0];
  float base[NK_];
#pragma unroll
  for (int k = 0; k < NK_; ++k)
    base[k] = (wsum + vb) + (float)mask[b * NK_ + k] * (-1e9f);   // fp32 absorption == ref

  const unsigned short* qrow = qp + (long)b * NQ_ * E_ + lane * 8;
  u16x8 qv = *(const u16x8*)qrow;

  float4* o0 = (float4*)(out0 + (long)b * NQ_ * E_) + lane * 2;
  float*  o1 = out1 + (long)b * (NQ_ * NK_);

  for (int qi = 0; qi < NQ_; ++qi){
    // prefetch next q row (hides HBM latency under this iteration's compute)
    u16x8 qn = qv;
    if (qi < NQ_ - 1) qn = *(const u16x8*)(qrow + (qi + 1) * E_);

    float qf[8];
#pragma unroll
    for (int j = 0; j < 8; ++j) qf[j] = bf2f((unsigned short)qv[j]);
    qv = qn;

    // hot loop: 7 independent accumulator chains
    float acc[NK_];
#pragma unroll
    for (int k = 0; k < NK_; ++k){
      float a = 0.f;
#pragma unroll
      for (int j = 0; j < 8; ++j){
        float x = qf[j] + kf[k][j];                  // 2*log2e*(q+k)
        float e = __builtin_amdgcn_exp2f(x);         // e^{2(q+k)}
        float r = __builtin_amdgcn_rcpf(e + 1.0f);   // sigmoid(-2(q+k))
        a = fmaf(wvr[j], r, a);
      }
      acc[k] = a;
    }
    // 7 independent butterflies (chains pipeline)
#pragma unroll
    for (int k = 0; k < NK_; ++k){
      float a = acc[k];
#pragma unroll
      for (int off = 32; off; off >>= 1) a += __shfl_xor(a, off, 64);
      acc[k] = a;
    }
    // scores + 7-wide softmax (all lanes redundantly, registers only)
    float sc[NK_], mx = -3.4e38f;
#pragma unroll
    for (int k = 0; k < NK_; ++k){ sc[k] = fmaf(-2.f, acc[k], base[k]); mx = fmaxf(mx, sc[k]); }
    float sum = 0.f;
#pragma unroll
    for (int k = 0; k < NK_; ++k){ sc[k] = __expf(sc[k] - mx); sum += sc[k]; }
    const float inv = __builtin_amdgcn_rcpf(sum);
    float wgt[NK_];
#pragma unroll
    for (int k = 0; k < NK_; ++k) wgt[k] = sc[k] * inv;

    // attn_weights: lanes 0..6 write wgt[lane] (branchless select)
    float wsel = wgt[0];
#pragma unroll
    for (int k = 1; k < NK_; ++k) wsel = (lane == k) ? wgt[k] : wsel;
    if (lane < NK_) o1[qi * NK_ + lane] = wsel;

    // attn_out = weights @ raw keys (all in registers)
    float4 lo = {0.f,0.f,0.f,0.f}, hi = {0.f,0.f,0.f,0.f};
#pragma unroll
    for (int k = 0; k < NK_; ++k){
      lo.x = fmaf(wgt[k], kr[k][0], lo.x);
      lo.y = fmaf(wgt[k], kr[k][1], lo.y);
      lo.z = fmaf(wgt[k], kr[k][2], lo.z);
      lo.w = fmaf(wgt[k], kr[k][3], lo.w);
      hi.x = fmaf(wgt[k], kr[k][4], hi.x);
      hi.y = fmaf(wgt[k], kr[k][5], hi.y);
      hi.z = fmaf(wgt[k], kr[k][6], hi.z);
      hi.w = fmaf(wgt[k], kr[k][7], hi.w);
    }
    o0[qi * 128 + 0] = lo;
    o0[qi * 128 + 1] = hi;
  }
}

// ---------------- launcher ----------------
extern "C" void kernel_launch(void* const* d_in, const int* in_sizes, int n_in,
                              void* d_out, int out_size, void* d_ws, size_t ws_size,
                              hipStream_t stream)
{
  const float* queries = (const float*)d_in[0];
  const float* keys    = (const float*)d_in[1];
  const float* wq_w    = (const float*)d_in[2];
  const float* wq_b    = (const float*)d_in[3];
  const float* wk_w    = (const float*)d_in[4];
  const float* wk_b    = (const float*)d_in[5];
  const float* wv_w    = (const float*)d_in[6];
  const float* wv_b    = (const float*)d_in[7];
  const int*   mask    = (const int*)d_in[8];
  (void)in_sizes; (void)n_in; (void)out_size; (void)ws_size;

  float* out0 = (float*)d_out;
  float* out1 = out0 + (long)MQ_ * E_;

  char* ws = (char*)d_ws;
  unsigned short* wqb = (unsigned short*)ws;                       // 512 KB
  unsigned short* wkb = (unsigned short*)(ws + 512 * 512 * 2);     // 512 KB
  unsigned short* qb  = (unsigned short*)(ws + (1 << 20));         // 88.1 MB
  unsigned short* kb  = qb + (size_t)MQ_ * E_;                     // 29.4 MB

  cast_weights<<<dim3(256), dim3(256), 0, stream>>>(wq_w, wk_w, (unsigned int*)wqb, (unsigned int*)wkb);
  gemm_proj<<<dim3(MTT_ * 2), dim3(256), 0, stream>>>(
      queries, keys, wqb, wkb, wq_b, wk_b, qb, kb);
  attn_fused<<<dim3(BS_ / 4), dim3(256), 0, stream>>>(qb, kb, keys, wv_w, wv_b, mask, out0, out1);
}

// Round 12
// 289.851 us; speedup vs baseline: 1.0121x; 1.0121x over previous
//
#include <hip/hip_runtime.h>
#include <hip/hip_bf16.h>

#define BS_   4096
#define NQ_   21
#define NK_   7
#define E_    512
#define MQ_   (BS_*NQ_)   // 86016 q rows
#define MK_   (BS_*NK_)   // 28672 k rows
#define MTQ_  (MQ_/64)    // 1344 q 64-row tiles
#define MTT_  ((MQ_+MK_)/64) // 1792 total 64-row tiles
#define SCALE_ 2.88539008177792681f   // 2*log2(e): exp2(SCALE*x) = e^{2x}

typedef __attribute__((ext_vector_type(8))) short bf16x8;
typedef __attribute__((ext_vector_type(4))) float f32x4;
typedef __attribute__((ext_vector_type(8))) unsigned short u16x8;

__device__ __forceinline__ unsigned int cvt_pk_bf16(float lo, float hi){
  unsigned int r;
  asm("v_cvt_pk_bf16_f32 %0, %1, %2" : "=v"(r) : "v"(lo), "v"(hi));
  return r;
}
__device__ __forceinline__ float bf2f(unsigned short h){
  return __builtin_bit_cast(float, (unsigned int)h << 16);
}

// ---------------- weight cast f32 -> bf16 ----------------
__global__ __launch_bounds__(256) void cast_weights(
    const float* __restrict__ wq, const float* __restrict__ wk,
    unsigned int* __restrict__ oq, unsigned int* __restrict__ ok)
{
  int i = blockIdx.x * 256 + threadIdx.x;           // 65536 float4s each
  float4 a = ((const float4*)wq)[i];
  float4 b = ((const float4*)wk)[i];
  uint2 ua = { cvt_pk_bf16(a.x, a.y), cvt_pk_bf16(a.z, a.w) };
  uint2 ub = { cvt_pk_bf16(b.x, b.y), cvt_pk_bf16(b.z, b.w) };
  ((uint2*)oq)[i] = ua;
  ((uint2*)ok)[i] = ub;
}

// ---------------- merged projection GEMMs: A-resident LDS, barrier-free K-loop
// C[m,h] = (sum_e A[m,e]*W[h,e] + bias[h]) * SCALE, bf16 out.
// Block = 64 rows x 512 cols (full N, full K); 4 waves col-split (128 cols ea).
// The ENTIRE 64x512 bf16 A-tile (64 KB) is staged to LDS ONCE (reg-staged,
// cvt_pk, XOR-swizzled), then ONE __syncthreads, then a free-running K-loop:
// no barriers, no LDS double-buffering. B (512 KB L2-resident weights) is
// read directly per-lane with ping-pong register prefetch; per-step address
// math is a compile-time immediate on 8 precomputed base pointers.
// LDS swizzle: logical 16B slot j of row r stored at j ^ (r&7)
//   -> frag reads (lanes 0-15 = 16 rows, same slot) spread over 8 slot groups
//      = 2-way (free); staged writes are ~4-way once (trivial).
__global__ __launch_bounds__(256)
void gemm_proj(const float* __restrict__ Aq, const float* __restrict__ Ak,
               const unsigned short* __restrict__ Bq, const unsigned short* __restrict__ Bk,
               const float* __restrict__ bq, const float* __restrict__ bk,
               unsigned short* __restrict__ Cq, unsigned short* __restrict__ Ck)
{
  __shared__ char Asm[64 * 1024];   // 64 KB: bf16 A-tile [64 rows][1024 B]

  const int tid  = threadIdx.x;
  const int lane = tid & 63;
  const int w    = tid >> 6;        // 0..3: 128-col slice
  const int l15  = lane & 15;
  const int s4   = lane >> 4;       // 0..3: k-slot

  // XCD-grouped bijection (1792 % 8 == 0)
  const int orig = (int)blockIdx.x;
  int mt = (orig & 7) * (MTT_ / 8) + (orig >> 3);

  const float* A; const unsigned short* Bw; const float* bias; unsigned short* C;
  if (mt < MTQ_){ A = Aq; Bw = Bq; bias = bq; C = Cq; }
  else          { A = Ak; Bw = Bk; bias = bk; C = Ck; mt -= MTQ_; }

  const long m0  = (long)mt << 6;            // 64-row tile base
  const int  n0w = w << 7;                   // this wave's 128-col base
  const char* Abyte = (const char*)(A + m0 * E_);

  // ---- B per-lane base pointers (8 n-frags of 16 cols each)
  const unsigned short* Bpn[8];
#pragma unroll
  for (int n = 0; n < 8; ++n)
    Bpn[n] = Bw + (long)(n0w + n * 16 + l15) * E_ + s4 * 8;

  // ---- A fragment-read offsets: byte(t) = (t&1 ? aoffO : aoffE)[m] + t*64
  int aoffE[4], aoffO[4];
#pragma unroll
  for (int m = 0; m < 4; ++m){
    const int r  = m * 16 + l15;
    const int b2 = (r >> 2) & 1;
    const int bs = r * 1024 + ((s4 ^ (r & 3)) << 4);
    aoffE[m] = bs + b2 * 64;
    aoffO[m] = bs - b2 * 64;
  }

  f32x4 acc[4][8];
  const f32x4 z4 = {0.f, 0.f, 0.f, 0.f};
#pragma unroll
  for (int m = 0; m < 4; ++m)
#pragma unroll
    for (int n = 0; n < 8; ++n) acc[m][n] = z4;

  bf16x8 b0[8], b1[8];

  // prefetch B k-step 0 (independent of LDS)
#pragma unroll
  for (int n = 0; n < 8; ++n)
    b0[n] = *(const bf16x8*)((const char*)Bpn[n]);

  // ---- stage full A-tile: 32 chunks/thread (16B f32 -> 8B bf16), 4 groups,
  //      depth-2 pipelined issue/write
#define AISSUE(buf, g) do { \
  _Pragma("unroll") for (int ii = 0; ii < 8; ++ii){ \
    const int c_ = tid + ((g) * 8 + ii) * 256; \
    buf[ii] = *(const float4*)(Abyte + (long)(c_ >> 7) * 2048 + (c_ & 127) * 16); \
  } \
} while(0)
#define AWRITE(buf, g) do { \
  _Pragma("unroll") for (int ii = 0; ii < 8; ++ii){ \
    const int c_ = tid + ((g) * 8 + ii) * 256; \
    const int row_ = c_ >> 7, sl_ = c_ & 127; \
    uint2 u_ = { cvt_pk_bf16(buf[ii].x, buf[ii].y), cvt_pk_bf16(buf[ii].z, buf[ii].w) }; \
    *(uint2*)(Asm + row_ * 1024 + (((sl_ >> 1) ^ (row_ & 7)) << 4) + (sl_ & 1) * 8) = u_; \
  } \
} while(0)

  {
    float4 avX[8], avY[8];
    AISSUE(avX, 0);
    AISSUE(avY, 1);
    AWRITE(avX, 0);
    AISSUE(avX, 2);
    AWRITE(avY, 1);
    AISSUE(avY, 3);
    AWRITE(avX, 2);
    AWRITE(avY, 3);
  }
  __syncthreads();   // the ONLY barrier

  // ---- free-running K-loop: 16 steps of K=32, ping-pong B prefetch
#define KSTEP(T, BCUR, BNXT) do { \
  if ((T) < 15){ \
    _Pragma("unroll") for (int n_ = 0; n_ < 8; ++n_) \
      BNXT[n_] = *(const bf16x8*)((const char*)Bpn[n_] + ((T) + 1) * 64); \
  } \
  bf16x8 af_[4]; \
  _Pragma("unroll") for (int m_ = 0; m_ < 4; ++m_) \
    af_[m_] = *(const bf16x8*)(Asm + (((T) & 1) ? aoffO[m_] : aoffE[m_]) + (T) * 64); \
  _Pragma("unroll") for (int m_ = 0; m_ < 4; ++m_) \
    _Pragma("unroll") for (int n_ = 0; n_ < 8; ++n_) \
      acc[m_][n_] = __builtin_amdgcn_mfma_f32_16x16x32_bf16(af_[m_], BCUR[n_], acc[m_][n_], 0, 0, 0); \
} while(0)

#pragma unroll
  for (int tp = 0; tp < 8; ++tp){
    KSTEP(2 * tp,     b0, b1);
    KSTEP(2 * tp + 1, b1, b0);
  }

#undef AISSUE
#undef AWRITE
#undef KSTEP

  // ---- epilogue: v = (acc + bias)*SCALE, bf16 store
  // C/D layout: col = lane&15 (+n*16), row = (lane>>4)*4 + j
  const int ccol0 = n0w + l15;
  float bvs[8];
#pragma unroll
  for (int n = 0; n < 8; ++n) bvs[n] = bias[ccol0 + n * 16] * SCALE_;
#pragma unroll
  for (int m = 0; m < 4; ++m){
    const long rbase = m0 + m * 16 + s4 * 4;
#pragma unroll
    for (int n = 0; n < 8; ++n){
      const long col = ccol0 + n * 16;
      float v0 = fmaf(acc[m][n][0], SCALE_, bvs[n]);
      float v1 = fmaf(acc[m][n][1], SCALE_, bvs[n]);
      float v2 = fmaf(acc[m][n][2], SCALE_, bvs[n]);
      float v3 = fmaf(acc[m][n][3], SCALE_, bvs[n]);
      unsigned int u01 = cvt_pk_bf16(v0, v1);
      unsigned int u23 = cvt_pk_bf16(v2, v3);
      C[(rbase + 0) * E_ + col] = (unsigned short)(u01 & 0xffffu);
      C[(rbase + 1) * E_ + col] = (unsigned short)(u01 >> 16);
      C[(rbase + 2) * E_ + col] = (unsigned short)(u23 & 0xffffu);
      C[(rbase + 3) * E_ + col] = (unsigned short)(u23 >> 16);
    }
  }
}

// ---------------- fused score + softmax + weighted sum ----------------
// One WAVE per batch. q'', k'' are bf16 pre-scaled by 2*log2(e).
// score(q,k) = sum_h wv_h * tanh(q+k) = Wsum - 2*sum_h wv_h / (1 + e^{2(q+k)})
__global__ __launch_bounds__(256, 2)
void attn_fused(const unsigned short* __restrict__ qp,
                const unsigned short* __restrict__ kp,
                const float* __restrict__ keys,
                const float* __restrict__ wv, const float* __restrict__ wvb,
                const int* __restrict__ mask,
                float* __restrict__ out0, float* __restrict__ out1)
{
  const int lane = threadIdx.x & 63;
  const int b    = blockIdx.x * 4 + (threadIdx.x >> 6);

  // per-lane wv slice (h = lane*8 .. +7)
  float wvr[8];
  *(float4*)&wvr[0] = ((const float4*)wv)[lane * 2];
  *(float4*)&wvr[4] = ((const float4*)wv)[lane * 2 + 1];

  // k'' rows -> f32 regs [7][8]
  float kf[NK_][8];
#pragma unroll
  for (int k = 0; k < NK_; ++k){
    u16x8 u = *(const u16x8*)(kp + ((long)b * NK_ + k) * E_ + lane * 8);
#pragma unroll
    for (int j = 0; j < 8; ++j) kf[k][j] = bf2f((unsigned short)u[j]);
  }
  // raw keys -> f32 regs [7][8]
  float kr[NK_][8];
#pragma unroll
  for (int k = 0; k < NK_; ++k){
    const float4* p = (const float4*)(keys + ((long)b * NK_ + k) * E_ + lane * 8);
    *(float4*)&kr[k][0] = p[0];
    *(float4*)&kr[k][4] = p[1];
  }

  // Wsum = sum_h wv_h (butterfly over lanes)
  float wsum = ((wvr[0] + wvr[1]) + (wvr[2] + wvr[3])) + ((wvr[4] + wvr[5]) + (wvr[6] + wvr[7]));
#pragma unroll
  for (int off = 32; off; off >>= 1) wsum += __shfl_xor(wsum, off, 64);

  const float vb = wvb[0];
  float base[NK_];
#pragma unroll
  for (int k = 0; k < NK_; ++k)
    base[k] = (wsum + vb) + (float)mask[b * NK_ + k] * (-1e9f);   // fp32 absorption == ref

  const unsigned short* qrow = qp + (long)b * NQ_ * E_ + lane * 8;
  u16x8 qv = *(const u16x8*)qrow;

  float4* o0 = (float4*)(out0 + (long)b * NQ_ * E_) + lane * 2;
  float*  o1 = out1 + (long)b * (NQ_ * NK_);

  for (int qi = 0; qi < NQ_; ++qi){
    // prefetch next q row (hides HBM latency under this iteration's compute)
    u16x8 qn = qv;
    if (qi < NQ_ - 1) qn = *(const u16x8*)(qrow + (qi + 1) * E_);

    float qf[8];
#pragma unroll
    for (int j = 0; j < 8; ++j) qf[j] = bf2f((unsigned short)qv[j]);
    qv = qn;

    // hot loop: 7 independent accumulator chains
    float acc[NK_];
#pragma unroll
    for (int k = 0; k < NK_; ++k){
      float a = 0.f;
#pragma unroll
      for (int j = 0; j < 8; ++j){
        float x = qf[j] + kf[k][j];                  // 2*log2e*(q+k)
        float e = __builtin_amdgcn_exp2f(x);         // e^{2(q+k)}
        float r = __builtin_amdgcn_rcpf(e + 1.0f);   // sigmoid(-2(q+k))
        a = fmaf(wvr[j], r, a);
      }
      acc[k] = a;
    }
    // 7 independent butterflies (chains pipeline)
#pragma unroll
    for (int k = 0; k < NK_; ++k){
      float a = acc[k];
#pragma unroll
      for (int off = 32; off; off >>= 1) a += __shfl_xor(a, off, 64);
      acc[k] = a;
    }
    // scores + 7-wide softmax (all lanes redundantly, registers only)
    float sc[NK_], mx = -3.4e38f;
#pragma unroll
    for (int k = 0; k < NK_; ++k){ sc[k] = fmaf(-2.f, acc[k], base[k]); mx = fmaxf(mx, sc[k]); }
    float sum = 0.f;
#pragma unroll
    for (int k = 0; k < NK_; ++k){ sc[k] = __expf(sc[k] - mx); sum += sc[k]; }
    const float inv = __builtin_amdgcn_rcpf(sum);
    float wgt[NK_];
#pragma unroll
    for (int k = 0; k < NK_; ++k) wgt[k] = sc[k] * inv;

    // attn_weights: lanes 0..6 write wgt[lane] (branchless select)
    float wsel = wgt[0];
#pragma unroll
    for (int k = 1; k < NK_; ++k) wsel = (lane == k) ? wgt[k] : wsel;
    if (lane < NK_) o1[qi * NK_ + lane] = wsel;

    // attn_out = weights @ raw keys (all in registers)
    float4 lo = {0.f,0.f,0.f,0.f}, hi = {0.f,0.f,0.f,0.f};
#pragma unroll
    for (int k = 0; k < NK_; ++k){
      lo.x = fmaf(wgt[k], kr[k][0], lo.x);
      lo.y = fmaf(wgt[k], kr[k][1], lo.y);
      lo.z = fmaf(wgt[k], kr[k][2], lo.z);
      lo.w = fmaf(wgt[k], kr[k][3], lo.w);
      hi.x = fmaf(wgt[k], kr[k][4], hi.x);
      hi.y = fmaf(wgt[k], kr[k][5], hi.y);
      hi.z = fmaf(wgt[k], kr[k][6], hi.z);
      hi.w = fmaf(wgt[k], kr[k][7], hi.w);
    }
    o0[qi * 128 + 0] = lo;
    o0[qi * 128 + 1] = hi;
  }
}

// ---------------- launcher ----------------
extern "C" void kernel_launch(void* const* d_in, const int* in_sizes, int n_in,
                              void* d_out, int out_size, void* d_ws, size_t ws_size,
                              hipStream_t stream)
{
  const float* queries = (const float*)d_in[0];
  const float* keys    = (const float*)d_in[1];
  const float* wq_w    = (const float*)d_in[2];
  const float* wq_b    = (const float*)d_in[3];
  const float* wk_w    = (const float*)d_in[4];
  const float* wk_b    = (const float*)d_in[5];
  const float* wv_w    = (const float*)d_in[6];
  const float* wv_b    = (const float*)d_in[7];
  const int*   mask    = (const int*)d_in[8];
  (void)in_sizes; (void)n_in; (void)out_size; (void)ws_size;

  float* out0 = (float*)d_out;
  float* out1 = out0 + (long)MQ_ * E_;

  char* ws = (char*)d_ws;
  unsigned short* wqb = (unsigned short*)ws;                       // 512 KB
  unsigned short* wkb = (unsigned short*)(ws + 512 * 512 * 2);     // 512 KB
  unsigned short* qb  = (unsigned short*)(ws + (1 << 20));         // 88.1 MB
  unsigned short* kb  = qb + (size_t)MQ_ * E_;                     // 29.4 MB

  cast_weights<<<dim3(256), dim3(256), 0, stream>>>(wq_w, wk_w, (unsigned int*)wqb, (unsigned int*)wkb);
  gemm_proj<<<dim3(MTT_), dim3(256), 0, stream>>>(
      queries, keys, wqb, wkb, wq_b, wk_b, qb, kb);
  attn_fused<<<dim3(BS_ / 4), dim3(256), 0, stream>>>(qb, kb, keys, wv_w, wv_b, mask, out0, out1);
}

// Round 13
// 289.074 us; speedup vs baseline: 1.0148x; 1.0027x over previous
//
#include <hip/hip_runtime.h>
#include <hip/hip_bf16.h>

#define BS_   4096
#define NQ_   21
#define NK_   7
#define E_    512
#define MQ_   (BS_*NQ_)
#define NB_   4                    // batches per fused block
#define NBLK_ (BS_/NB_)            // 1024 blocks
#define SCALE_ 2.88539008177792681f   // 2*log2(e): exp2(SCALE*x) = e^{2x}

typedef __attribute__((ext_vector_type(8))) short bf16x8;
typedef __attribute__((ext_vector_type(4))) float f32x4;
typedef __attribute__((ext_vector_type(8))) unsigned short u16x8;

__device__ __forceinline__ unsigned int cvt_pk_bf16(float lo, float hi){
  unsigned int r;
  asm("v_cvt_pk_bf16_f32 %0, %1, %2" : "=v"(r) : "v"(lo), "v"(hi));
  return r;
}
__device__ __forceinline__ unsigned short f2bfu(float x){
  return __builtin_bit_cast(unsigned short, __float2bfloat16(x));
}
__device__ __forceinline__ float bf2f(unsigned short h){
  return __builtin_bit_cast(float, (unsigned int)h << 16);
}

// ---------------- weight cast f32 -> bf16 ----------------
__global__ __launch_bounds__(256) void cast_weights(
    const float* __restrict__ wq, const float* __restrict__ wk,
    unsigned int* __restrict__ oq, unsigned int* __restrict__ ok)
{
  int i = blockIdx.x * 256 + threadIdx.x;           // 65536 float4s each
  float4 a = ((const float4*)wq)[i];
  float4 b = ((const float4*)wk)[i];
  uint2 ua = { cvt_pk_bf16(a.x, a.y), cvt_pk_bf16(a.z, a.w) };
  uint2 ub = { cvt_pk_bf16(b.x, b.y), cvt_pk_bf16(b.z, b.w) };
  ((uint2*)oq)[i] = ua;
  ((uint2*)ok)[i] = ub;
}

// ---------------- fully fused: projections + score + softmax + output -------
// Block = 4 batches, 512 threads (8 waves).
// GEMM phase: A-tile = [96 q-rows(84 real) ; 32 k-rows(28 real)] = 128 rows =
// 8 M-frags (frags 0-5 -> Wq, 6-7 -> Wk; pad rows clamp-read, discard on
// writeback). Waves split N 8-way (64 cols = 4 N-frags each); acc 8x4 f32x4 =
// 128 VGPR. K-loop: 8 steps of BK=64, double-buffered 16 KB LDS A-slices
// (f32 HBM -> cvt_pk -> XOR-swizzled bf16), B read directly from the
// L2-resident 1 MB bf16 weight panel (per-lane fragment loads, imm offsets).
// q'/k' = (acc+bias)*SCALE written to LDS as bf16 [112 rows][1024 B] (aliases
// the A-dbuf; never touches HBM), then the register-resident score phase
// (proven r1 structure) reads LDS and writes out0/out1.
__global__ __launch_bounds__(512, 2)
void fused_all(const float* __restrict__ queries, const float* __restrict__ keys,
               const unsigned short* __restrict__ Wq, const unsigned short* __restrict__ Wk,
               const float* __restrict__ bq, const float* __restrict__ bk,
               const float* __restrict__ wv, const float* __restrict__ wvb,
               const int* __restrict__ mask,
               float* __restrict__ out0, float* __restrict__ out1)
{
  __shared__ char SH[112 * 1024];   // 112 KB; first 32 KB doubles as A-dbuf

  const int tid  = threadIdx.x;
  const int lane = tid & 63;
  const int w    = tid >> 6;        // 0..7
  const int l15  = lane & 15;
  const int s4   = lane >> 4;
  const long B0  = (long)blockIdx.x * NB_;

  // ---- A staging map: 4 x (16B f32 -> 8B bf16) per thread per K-step
  const float* asrcp[4]; int adst[4];
#pragma unroll
  for (int i = 0; i < 4; ++i){
    const int c   = tid + i * 512;            // chunk 0..2047
    const int row = c >> 4;                   // 0..127 (16 chunks per row)
    const int sl  = c & 15;
    const float* src;
    if (row < 96) src = queries + (B0 * NQ_ + (row < 84 ? row : 83)) * E_;
    else          src = keys    + (B0 * NK_ + (row - 96 < 28 ? row - 96 : 27)) * E_;
    asrcp[i] = src + sl * 4;
    adst[i]  = row * 128 + (((sl >> 1) << 4) ^ ((row & 7) << 4)) + (sl & 1) * 8;
  }
  // ---- A fragment-read offsets (kk=1 is ^64: disjoint bit fields)
  int aoffm[8];
#pragma unroll
  for (int m = 0; m < 8; ++m)
    aoffm[m] = (16 * m + l15) * 128 + ((s4 * 16) ^ ((l15 & 7) << 4));
  // ---- B per-lane fragment pointers: 0-3 = Wq cols, 4-7 = Wk cols
  const unsigned short* Bptr[8];
#pragma unroll
  for (int n = 0; n < 4; ++n){
    const long col = w * 64 + n * 16 + l15;
    Bptr[n]     = Wq + col * E_ + s4 * 8;
    Bptr[4 + n] = Wk + col * E_ + s4 * 8;
  }

  f32x4 acc[8][4];
  const f32x4 z4 = {0.f, 0.f, 0.f, 0.f};
#pragma unroll
  for (int m = 0; m < 8; ++m)
#pragma unroll
    for (int n = 0; n < 4; ++n) acc[m][n] = z4;

#define ASTAGE_LD(av, STEP) do { \
  _Pragma("unroll") for (int i_ = 0; i_ < 4; ++i_) \
    av[i_] = *(const float4*)(asrcp[i_] + (STEP) * 64); \
} while(0)
#define ASTAGE_WR(av, BUF) do { \
  _Pragma("unroll") for (int i_ = 0; i_ < 4; ++i_){ \
    uint2 u_ = { cvt_pk_bf16(av[i_].x, av[i_].y), cvt_pk_bf16(av[i_].z, av[i_].w) }; \
    *(uint2*)(SH + (BUF) * 16384 + adst[i_]) = u_; \
  } \
} while(0)

  // ---- prologue
  {
    float4 av[4];
    ASTAGE_LD(av, 0);
    ASTAGE_WR(av, 0);
  }
  __syncthreads();

  // ---- K-loop: 8 steps of 64
#pragma unroll
  for (int st = 0; st < 8; ++st){
    const int buf = st & 1;
    float4 av[4];
    if (st < 7) ASTAGE_LD(av, st + 1);
#pragma unroll
    for (int kk = 0; kk < 2; ++kk){
      const int t = st * 2 + kk;
      bf16x8 bfr[8];
#pragma unroll
      for (int p = 0; p < 8; ++p)
        bfr[p] = *(const bf16x8*)((const char*)Bptr[p] + t * 64);
#pragma unroll
      for (int m = 0; m < 8; ++m){
        bf16x8 afm = *(const bf16x8*)(SH + buf * 16384 + (aoffm[m] ^ (kk ? 64 : 0)));
#pragma unroll
        for (int n = 0; n < 4; ++n)
          acc[m][n] = __builtin_amdgcn_mfma_f32_16x16x32_bf16(
                          afm, bfr[(m >= 6 ? 4 : 0) + n], acc[m][n], 0, 0, 0);
      }
    }
    if (st < 7) ASTAGE_WR(av, buf ^ 1);
    __syncthreads();   // last iteration's sync also fences the SH overwrite below
  }

#undef ASTAGE_LD
#undef ASTAGE_WR

  // ---- writeback: q'/k' = (acc + bias)*SCALE -> LDS bf16 [112][1024 B]
  {
    const int colb = w * 64 + l15;
    float bvq[4], bvk[4];
#pragma unroll
    for (int n = 0; n < 4; ++n){
      bvq[n] = bq[colb + n * 16] * SCALE_;
      bvk[n] = bk[colb + n * 16] * SCALE_;
    }
#pragma unroll
    for (int m = 0; m < 8; ++m)
#pragma unroll
      for (int n = 0; n < 4; ++n)
#pragma unroll
        for (int j = 0; j < 4; ++j){
          const int rl = s4 * 4 + j;
          const float v = fmaf(acc[m][n][j], SCALE_, (m < 6) ? bvq[n] : bvk[n]);
          if (m < 6){
            const int qrow = 16 * m + rl;
            if (qrow < 84)
              *(unsigned short*)(SH + qrow * 1024 + (colb + n * 16) * 2) = f2bfu(v);
          } else {
            const int krow = 16 * (m - 6) + rl;
            if (krow < 28)
              *(unsigned short*)(SH + (84 + krow) * 1024 + (colb + n * 16) * 2) = f2bfu(v);
          }
        }
  }
  __syncthreads();

  // ---- score + softmax + weighted-sum phase (r1-proven structure)
  const int  bl   = w >> 1;          // local batch 0..3
  const int  half = w & 1;
  const int  q0   = half * 11;
  const int  nq   = half ? 10 : 11;
  const long b    = B0 + bl;

  float wvr[8];
  *(float4*)&wvr[0] = ((const float4*)wv)[lane * 2];
  *(float4*)&wvr[4] = ((const float4*)wv)[lane * 2 + 1];

  float kf[NK_][8];
#pragma unroll
  for (int k = 0; k < NK_; ++k){
    u16x8 u = *(const u16x8*)(SH + (84 + bl * NK_ + k) * 1024 + lane * 16);
#pragma unroll
    for (int j = 0; j < 8; ++j) kf[k][j] = bf2f((unsigned short)u[j]);
  }
  float kr[NK_][8];
#pragma unroll
  for (int k = 0; k < NK_; ++k){
    const float4* p = (const float4*)(keys + (b * NK_ + k) * E_ + lane * 8);
    *(float4*)&kr[k][0] = p[0];
    *(float4*)&kr[k][4] = p[1];
  }

  float wsum = ((wvr[0] + wvr[1]) + (wvr[2] + wvr[3])) + ((wvr[4] + wvr[5]) + (wvr[6] + wvr[7]));
#pragma unroll
  for (int off = 32; off; off >>= 1) wsum += __shfl_xor(wsum, off, 64);

  const float vb = wvb[0];
  float base[NK_];
#pragma unroll
  for (int k = 0; k < NK_; ++k)
    base[k] = (wsum + vb) + (float)mask[b * NK_ + k] * (-1e9f);   // fp32 absorption == ref

  float4* o0 = (float4*)(out0 + (b * NQ_) * E_) + lane * 2;
  float*  o1 = out1 + b * (NQ_ * NK_);

  for (int qi = q0; qi < q0 + nq; ++qi){
    u16x8 qv = *(const u16x8*)(SH + (bl * NQ_ + qi) * 1024 + lane * 16);
    float qf[8];
#pragma unroll
    for (int j = 0; j < 8; ++j) qf[j] = bf2f((unsigned short)qv[j]);

    float acs[NK_];
#pragma unroll
    for (int k = 0; k < NK_; ++k){
      float a = 0.f;
#pragma unroll
      for (int j = 0; j < 8; ++j){
        float x = qf[j] + kf[k][j];                  // 2*log2e*(q+k)
        float e = __builtin_amdgcn_exp2f(x);         // e^{2(q+k)}
        float r = __builtin_amdgcn_rcpf(e + 1.0f);   // sigmoid(-2(q+k))
        a = fmaf(wvr[j], r, a);
      }
      acs[k] = a;
    }
#pragma unroll
    for (int k = 0; k < NK_; ++k){
      float a = acs[k];
#pragma unroll
      for (int off = 32; off; off >>= 1) a += __shfl_xor(a, off, 64);
      acs[k] = a;
    }
    float sc[NK_], mx = -3.4e38f;
#pragma unroll
    for (int k = 0; k < NK_; ++k){ sc[k] = fmaf(-2.f, acs[k], base[k]); mx = fmaxf(mx, sc[k]); }
    float sum = 0.f;
#pragma unroll
    for (int k = 0; k < NK_; ++k){ sc[k] = __expf(sc[k] - mx); sum += sc[k]; }
    const float inv = __builtin_amdgcn_rcpf(sum);
    float wgt[NK_];
#pragma unroll
    for (int k = 0; k < NK_; ++k) wgt[k] = sc[k] * inv;

    float wsel = wgt[0];
#pragma unroll
    for (int k = 1; k < NK_; ++k) wsel = (lane == k) ? wgt[k] : wsel;
    if (lane < NK_) o1[qi * NK_ + lane] = wsel;

    float4 lo = {0.f,0.f,0.f,0.f}, hi = {0.f,0.f,0.f,0.f};
#pragma unroll
    for (int k = 0; k < NK_; ++k){
      lo.x = fmaf(wgt[k], kr[k][0], lo.x);
      lo.y = fmaf(wgt[k], kr[k][1], lo.y);
      lo.z = fmaf(wgt[k], kr[k][2], lo.z);
      lo.w = fmaf(wgt[k], kr[k][3], lo.w);
      hi.x = fmaf(wgt[k], kr[k][4], hi.x);
      hi.y = fmaf(wgt[k], kr[k][5], hi.y);
      hi.z = fmaf(wgt[k], kr[k][6], hi.z);
      hi.w = fmaf(wgt[k], kr[k][7], hi.w);
    }
    o0[qi * 128 + 0] = lo;
    o0[qi * 128 + 1] = hi;
  }
}

// ---------------- launcher ----------------
extern "C" void kernel_launch(void* const* d_in, const int* in_sizes, int n_in,
                              void* d_out, int out_size, void* d_ws, size_t ws_size,
                              hipStream_t stream)
{
  const float* queries = (const float*)d_in[0];
  const float* keys    = (const float*)d_in[1];
  const float* wq_w    = (const float*)d_in[2];
  const float* wq_b    = (const float*)d_in[3];
  const float* wk_w    = (const float*)d_in[4];
  const float* wk_b    = (const float*)d_in[5];
  const float* wv_w    = (const float*)d_in[6];
  const float* wv_b    = (const float*)d_in[7];
  const int*   mask    = (const int*)d_in[8];
  (void)in_sizes; (void)n_in; (void)out_size; (void)ws_size;

  float* out0 = (float*)d_out;
  float* out1 = out0 + (long)MQ_ * E_;

  char* ws = (char*)d_ws;
  unsigned short* wqb = (unsigned short*)ws;                       // 512 KB
  unsigned short* wkb = (unsigned short*)(ws + 512 * 512 * 2);     // 512 KB

  cast_weights<<<dim3(256), dim3(256), 0, stream>>>(wq_w, wk_w, (unsigned int*)wqb, (unsigned int*)wkb);
  fused_all<<<dim3(NBLK_), dim3(512), 0, stream>>>(
      queries, keys, wqb, wkb, wq_b, wk_b, wv_w, wv_b, mask, out0, out1);
}

// Round 14
// 283.871 us; speedup vs baseline: 1.0334x; 1.0183x over previous
//
#include <hip/hip_runtime.h>
#include <hip/hip_bf16.h>

#define BS_   4096
#define NQ_   21
#define NK_   7
#define E_    512
#define MQ_   (BS_*NQ_)   // 86016 q rows
#define MK_   (BS_*NK_)   // 28672 k rows
#define MTQ_  (MQ_/256)   // 336 q 256-row tiles
#define MTT_  ((MQ_+MK_)/256) // 448 total tiles
#define SCALE_ 2.88539008177792681f   // 2*log2(e): exp2(SCALE*x) = e^{2x}

typedef __attribute__((ext_vector_type(8))) short bf16x8;
typedef __attribute__((ext_vector_type(4))) float f32x4;
typedef __attribute__((ext_vector_type(8))) unsigned short u16x8;

__device__ __forceinline__ unsigned int cvt_pk_bf16(float lo, float hi){
  unsigned int r;
  asm("v_cvt_pk_bf16_f32 %0, %1, %2" : "=v"(r) : "v"(lo), "v"(hi));
  return r;
}
__device__ __forceinline__ unsigned short f2bfu(float x){
  return __builtin_bit_cast(unsigned short, __float2bfloat16(x));
}
__device__ __forceinline__ float bf2f(unsigned short h){
  return __builtin_bit_cast(float, (unsigned int)h << 16);
}
__device__ __forceinline__ void gload_lds16(const void* g, void* l){
  __builtin_amdgcn_global_load_lds(
      (const __attribute__((address_space(1))) unsigned int*)g,
      (__attribute__((address_space(3))) unsigned int*)l, 16, 0, 0);
}

// ---------------- weight cast f32 -> bf16 ----------------
__global__ __launch_bounds__(256) void cast_weights(
    const float* __restrict__ wq, const float* __restrict__ wk,
    unsigned int* __restrict__ oq, unsigned int* __restrict__ ok)
{
  int i = blockIdx.x * 256 + threadIdx.x;           // 65536 float4s each
  float4 a = ((const float4*)wq)[i];
  float4 b = ((const float4*)wk)[i];
  uint2 ua = { cvt_pk_bf16(a.x, a.y), cvt_pk_bf16(a.z, a.w) };
  uint2 ub = { cvt_pk_bf16(b.x, b.y), cvt_pk_bf16(b.z, b.w) };
  ((uint2*)oq)[i] = ua;
  ((uint2*)ok)[i] = ub;
}

// ---------------- merged projection GEMMs: fat barrier-steps ----------------
// C[m,h] = (sum_e A[m,e]*W[h,e] + bias[h]) * SCALE, bf16 out.
// Block = 256 rows x 128 cols, 4 waves M-split (64 rows each), wave tile
// 64x128 -> acc 4x8 (128 VGPR), 32 MFMA per wave per K-step (2x r10's 16).
// BK=32, 16 K-steps, block-steps halved vs r10 (28672 total).
// BOTH operands DMA'd via global_load_lds (linear dest, pre-swizzled source):
//   A: f32 LDS tile [256 rows][128 B], slot(16B) ^= (row&7)  -> frag reads
//      2-way (free); converted f32->bf16 at read via r4-proven union+f2bfu.
//   B: bf16 LDS tile [128 rows][64 B], r10's byte-identical map (0 conflicts).
// m97-style schedule: stage(t+1) -> compute(t) -> __syncthreads (drains the
// just-issued DMAs after ~620 matrix-cycles in flight).
// LDS = 2*(32K A + 8K B) = 80 KB -> exactly 2 blocks/CU.
__global__ __launch_bounds__(256)
void gemm_proj(const float* __restrict__ Aq, const float* __restrict__ Ak,
               const unsigned short* __restrict__ Bq, const unsigned short* __restrict__ Bk,
               const float* __restrict__ bq, const float* __restrict__ bk,
               unsigned short* __restrict__ Cq, unsigned short* __restrict__ Ck)
{
  __shared__ char SH[81920];   // A: [0,32768),[32768,65536)  B: [65536,73728),[73728,81920)

  const int tid  = threadIdx.x;
  const int lane = tid & 63;
  const int w    = tid >> 6;        // 0..3: 64-row M slice
  const int l15  = lane & 15;
  const int s4   = lane >> 4;

  // XCD-grouped bijection (1792 % 8 == 0): nt fastest within an XCD.
  const int orig = (int)blockIdx.x;
  const int xcd  = orig & 7, idx = orig >> 3;      // idx 0..223
  int       mt   = xcd * 56 + (idx >> 2);          // 0..447
  const int nt   = idx & 3;

  const float* A; const unsigned short* Bw; const float* bias; unsigned short* C;
  if (mt < MTQ_){ A = Aq; Bw = Bq; bias = bq; C = Cq; }
  else          { A = Ak; Bw = Bk; bias = bk; C = Ck; mt -= MTQ_; }

  const long m0 = (long)mt << 8;            // 256-row tile base
  const int  n0 = nt << 7;                  // 128-col base
  const char* Abyte = (const char*)(A + m0 * E_);
  const char* Bbyte = (const char*)Bw;

  // ---- A staging map: 8 x 16B DMA per thread per K-step (pre-swizzled src)
  long asrc[8]; int adst[8];
#pragma unroll
  for (int i = 0; i < 8; ++i){
    const int c   = tid + i * 256;          // chunk 0..2047
    const int row = c >> 3;                 // 8 slots of 16B per 128-B k-window
    const int sl  = c & 7;
    asrc[i] = (long)row * 2048 + ((sl ^ (row & 7)) << 4);
    adst[i] = c << 4;                       // linear dest (DMA requirement)
  }
  // ---- B staging map: 2 x 16B DMA per thread per K-step (r10-identical)
  long bsrc[2]; int bdst[2];
#pragma unroll
  for (int i = 0; i < 2; ++i){
    const int c   = tid + i * 256;          // chunk 0..511
    const int row = c >> 2;                 // 4 slots per 64-B row
    const int sl  = c & 3;
    bsrc[i] = (long)(n0 + row) * 1024 + ((sl << 4) ^ (((row >> 1) & 3) << 4));
    bdst[i] = c << 4;
  }

  // ---- fragment-read byte offsets (loop-invariant)
  int aoff0[4], aoff1[4], boff[8];
#pragma unroll
  for (int m = 0; m < 4; ++m){
    const int r = w * 64 + m * 16 + l15;
    aoff0[m] = r * 128 + (((s4 * 2)     ^ (r & 7)) << 4);
    aoff1[m] = r * 128 + (((s4 * 2 + 1) ^ (r & 7)) << 4);
  }
#pragma unroll
  for (int n = 0; n < 8; ++n){
    const int r = n * 16 + l15;
    boff[n] = r * 64 + ((s4 << 4) ^ (((r >> 1) & 3) << 4));
  }

  f32x4 acc[4][8];
  const f32x4 z4 = {0.f, 0.f, 0.f, 0.f};
#pragma unroll
  for (int m = 0; m < 4; ++m)
#pragma unroll
    for (int n = 0; n < 8; ++n) acc[m][n] = z4;

  union U8 { unsigned short s[8]; bf16x8 v; };

#define STAGE(T, PH) do { \
  _Pragma("unroll") for (int i_ = 0; i_ < 8; ++i_) \
    gload_lds16(Abyte + asrc[i_] + (long)(T) * 128, SH + (PH) * 32768 + adst[i_]); \
  _Pragma("unroll") for (int i_ = 0; i_ < 2; ++i_) \
    gload_lds16(Bbyte + bsrc[i_] + (T) * 64, SH + 65536 + (PH) * 8192 + bdst[i_]); \
} while(0)

#define COMPUTE(PH) do { \
  const char* ab_ = SH + (PH) * 32768; \
  const char* bb_ = SH + 65536 + (PH) * 8192; \
  bf16x8 af_[4], bfr_[8]; \
  _Pragma("unroll") for (int m_ = 0; m_ < 4; ++m_){ \
    f32x4 lo_ = *(const f32x4*)(ab_ + aoff0[m_]); \
    f32x4 hi_ = *(const f32x4*)(ab_ + aoff1[m_]); \
    U8 u_; \
    u_.s[0] = f2bfu(lo_[0]); u_.s[1] = f2bfu(lo_[1]); \
    u_.s[2] = f2bfu(lo_[2]); u_.s[3] = f2bfu(lo_[3]); \
    u_.s[4] = f2bfu(hi_[0]); u_.s[5] = f2bfu(hi_[1]); \
    u_.s[6] = f2bfu(hi_[2]); u_.s[7] = f2bfu(hi_[3]); \
    af_[m_] = u_.v; \
  } \
  _Pragma("unroll") for (int n_ = 0; n_ < 8; ++n_) \
    bfr_[n_] = *(const bf16x8*)(bb_ + boff[n_]); \
  _Pragma("unroll") for (int m_ = 0; m_ < 4; ++m_) \
    _Pragma("unroll") for (int n_ = 0; n_ < 8; ++n_) \
      acc[m_][n_] = __builtin_amdgcn_mfma_f32_16x16x32_bf16(af_[m_], bfr_[n_], acc[m_][n_], 0, 0, 0); \
} while(0)

  // ---- prologue
  STAGE(0, 0);
  __syncthreads();

  // ---- main loop: 16 K-steps of 32
#pragma unroll
  for (int t = 0; t < 16; ++t){
    if (t < 15) STAGE(t + 1, (t + 1) & 1);
    COMPUTE(t & 1);
    __syncthreads();
  }

#undef STAGE
#undef COMPUTE

  // ---- epilogue: v = (acc + bias)*SCALE, bf16 store
  // C/D layout: col = lane&15 (+n*16), row = (lane>>4)*4 + j
  const int ccol0 = n0 + l15;
  float bvs[8];
#pragma unroll
  for (int n = 0; n < 8; ++n) bvs[n] = bias[ccol0 + n * 16] * SCALE_;
#pragma unroll
  for (int m = 0; m < 4; ++m){
    const long rbase = m0 + w * 64 + m * 16 + s4 * 4;
#pragma unroll
    for (int n = 0; n < 8; ++n){
      const long col = ccol0 + n * 16;
      float v0 = fmaf(acc[m][n][0], SCALE_, bvs[n]);
      float v1 = fmaf(acc[m][n][1], SCALE_, bvs[n]);
      float v2 = fmaf(acc[m][n][2], SCALE_, bvs[n]);
      float v3 = fmaf(acc[m][n][3], SCALE_, bvs[n]);
      unsigned int u01 = cvt_pk_bf16(v0, v1);
      unsigned int u23 = cvt_pk_bf16(v2, v3);
      C[(rbase + 0) * E_ + col] = (unsigned short)(u01 & 0xffffu);
      C[(rbase + 1) * E_ + col] = (unsigned short)(u01 >> 16);
      C[(rbase + 2) * E_ + col] = (unsigned short)(u23 & 0xffffu);
      C[(rbase + 3) * E_ + col] = (unsigned short)(u23 >> 16);
    }
  }
}

// ---------------- fused score + softmax + weighted sum ----------------
// One WAVE per batch. q'', k'' are bf16 pre-scaled by 2*log2(e).
// score(q,k) = sum_h wv_h * tanh(q+k) = Wsum - 2*sum_h wv_h / (1 + e^{2(q+k)})
__global__ __launch_bounds__(256, 2)
void attn_fused(const unsigned short* __restrict__ qp,
                const unsigned short* __restrict__ kp,
                const float* __restrict__ keys,
                const float* __restrict__ wv, const float* __restrict__ wvb,
                const int* __restrict__ mask,
                float* __restrict__ out0, float* __restrict__ out1)
{
  const int lane = threadIdx.x & 63;
  const int b    = blockIdx.x * 4 + (threadIdx.x >> 6);

  // per-lane wv slice (h = lane*8 .. +7)
  float wvr[8];
  *(float4*)&wvr[0] = ((const float4*)wv)[lane * 2];
  *(float4*)&wvr[4] = ((const float4*)wv)[lane * 2 + 1];

  // k'' rows -> f32 regs [7][8]
  float kf[NK_][8];
#pragma unroll
  for (int k = 0; k < NK_; ++k){
    u16x8 u = *(const u16x8*)(kp + ((long)b * NK_ + k) * E_ + lane * 8);
#pragma unroll
    for (int j = 0; j < 8; ++j) kf[k][j] = bf2f((unsigned short)u[j]);
  }
  // raw keys -> f32 regs [7][8]
  float kr[NK_][8];
#pragma unroll
  for (int k = 0; k < NK_; ++k){
    const float4* p = (const float4*)(keys + ((long)b * NK_ + k) * E_ + lane * 8);
    *(float4*)&kr[k][0] = p[0];
    *(float4*)&kr[k][4] = p[1];
  }

  // Wsum = sum_h wv_h (butterfly over lanes)
  float wsum = ((wvr[0] + wvr[1]) + (wvr[2] + wvr[3])) + ((wvr[4] + wvr[5]) + (wvr[6] + wvr[7]));
#pragma unroll
  for (int off = 32; off; off >>= 1) wsum += __shfl_xor(wsum, off, 64);

  const float vb = wvb[0];
  float base[NK_];
#pragma unroll
  for (int k = 0; k < NK_; ++k)
    base[k] = (wsum + vb) + (float)mask[b * NK_ + k] * (-1e9f);   // fp32 absorption == ref

  const unsigned short* qrow = qp + (long)b * NQ_ * E_ + lane * 8;
  u16x8 qv = *(const u16x8*)qrow;

  float4* o0 = (float4*)(out0 + (long)b * NQ_ * E_) + lane * 2;
  float*  o1 = out1 + (long)b * (NQ_ * NK_);

  for (int qi = 0; qi < NQ_; ++qi){
    // prefetch next q row (hides HBM latency under this iteration's compute)
    u16x8 qn = qv;
    if (qi < NQ_ - 1) qn = *(const u16x8*)(qrow + (qi + 1) * E_);

    float qf[8];
#pragma unroll
    for (int j = 0; j < 8; ++j) qf[j] = bf2f((unsigned short)qv[j]);
    qv = qn;

    // hot loop: 7 independent accumulator chains
    float acc[NK_];
#pragma unroll
    for (int k = 0; k < NK_; ++k){
      float a = 0.f;
#pragma unroll
      for (int j = 0; j < 8; ++j){
        float x = qf[j] + kf[k][j];                  // 2*log2e*(q+k)
        float e = __builtin_amdgcn_exp2f(x);         // e^{2(q+k)}
        float r = __builtin_amdgcn_rcpf(e + 1.0f);   // sigmoid(-2(q+k))
        a = fmaf(wvr[j], r, a);
      }
      acc[k] = a;
    }
    // 7 independent butterflies (chains pipeline)
#pragma unroll
    for (int k = 0; k < NK_; ++k){
      float a = acc[k];
#pragma unroll
      for (int off = 32; off; off >>= 1) a += __shfl_xor(a, off, 64);
      acc[k] = a;
    }
    // scores + 7-wide softmax (all lanes redundantly, registers only)
    float sc[NK_], mx = -3.4e38f;
#pragma unroll
    for (int k = 0; k < NK_; ++k){ sc[k] = fmaf(-2.f, acc[k], base[k]); mx = fmaxf(mx, sc[k]); }
    float sum = 0.f;
#pragma unroll
    for (int k = 0; k < NK_; ++k){ sc[k] = __expf(sc[k] - mx); sum += sc[k]; }
    const float inv = __builtin_amdgcn_rcpf(sum);
    float wgt[NK_];
#pragma unroll
    for (int k = 0; k < NK_; ++k) wgt[k] = sc[k] * inv;

    // attn_weights: lanes 0..6 write wgt[lane] (branchless select)
    float wsel = wgt[0];
#pragma unroll
    for (int k = 1; k < NK_; ++k) wsel = (lane == k) ? wgt[k] : wsel;
    if (lane < NK_) o1[qi * NK_ + lane] = wsel;

    // attn_out = weights @ raw keys (all in registers)
    float4 lo = {0.f,0.f,0.f,0.f}, hi = {0.f,0.f,0.f,0.f};
#pragma unroll
    for (int k = 0; k < NK_; ++k){
      lo.x = fmaf(wgt[k], kr[k][0], lo.x);
      lo.y = fmaf(wgt[k], kr[k][1], lo.y);
      lo.z = fmaf(wgt[k], kr[k][2], lo.z);
      lo.w = fmaf(wgt[k], kr[k][3], lo.w);
      hi.x = fmaf(wgt[k], kr[k][4], hi.x);
      hi.y = fmaf(wgt[k], kr[k][5], hi.y);
      hi.z = fmaf(wgt[k], kr[k][6], hi.z);
      hi.w = fmaf(wgt[k], kr[k][7], hi.w);
    }
    o0[qi * 128 + 0] = lo;
    o0[qi * 128 + 1] = hi;
  }
}

// ---------------- launcher ----------------
extern "C" void kernel_launch(void* const* d_in, const int* in_sizes, int n_in,
                              void* d_out, int out_size, void* d_ws, size_t ws_size,
                              hipStream_t stream)
{
  const float* queries = (const float*)d_in[0];
  const float* keys    = (const float*)d_in[1];
  const float* wq_w    = (const float*)d_in[2];
  const float* wq_b    = (const float*)d_in[3];
  const float* wk_w    = (const float*)d_in[4];
  const float* wk_b    = (const float*)d_in[5];
  const float* wv_w    = (const float*)d_in[6];
  const float* wv_b    = (const float*)d_in[7];
  const int*   mask    = (const int*)d_in[8];
  (void)in_sizes; (void)n_in; (void)out_size; (void)ws_size;

  float* out0 = (float*)d_out;
  float* out1 = out0 + (long)MQ_ * E_;

  char* ws = (char*)d_ws;
  unsigned short* wqb = (unsigned short*)ws;                       // 512 KB
  unsigned short* wkb = (unsigned short*)(ws + 512 * 512 * 2);     // 512 KB
  unsigned short* qb  = (unsigned short*)(ws + (1 << 20));         // 88.1 MB
  unsigned short* kb  = qb + (size_t)MQ_ * E_;                     // 29.4 MB

  cast_weights<<<dim3(256), dim3(256), 0, stream>>>(wq_w, wk_w, (unsigned int*)wqb, (unsigned int*)wkb);
  gemm_proj<<<dim3(MTT_ * 4), dim3(256), 0, stream>>>(
      queries, keys, wqb, wkb, wq_b, wk_b, qb, kb);
  attn_fused<<<dim3(BS_ / 4), dim3(256), 0, stream>>>(qb, kb, keys, wv_w, wv_b, mask, out0, out1);
}